// Round 6
// baseline (1948.506 us; speedup 1.0000x reference)
//
#include <hip/hip_runtime.h>
#include <math.h>

#define HH 4
#define FF 1024          // 2*d floats per complex vector
#define NN 2048
#define KK 4
#define TMAXI 4
#define THRESHV 0.99f
#define EPSV 1e-6f
#define NG 8             // col groups (2 per head)
#define GW 1024          // cols per group
#define RB 64            // rows per gemm block
#define CTILE 128        // col tile
#define BKE 32           // K-chunk elems

typedef unsigned short ushort_t;
typedef __attribute__((ext_vector_type(8))) __bf16 bf16x8;
typedef __attribute__((ext_vector_type(4))) float f32x4;
typedef __attribute__((ext_vector_type(4))) unsigned short us4;

__device__ __forceinline__ unsigned short f2bf(float x) {
    unsigned int u = __float_as_uint(x);
    unsigned int r = (u + 0x7FFF + ((u >> 16) & 1)) >> 16;
    return (unsigned short)r;
}

typedef __attribute__((address_space(3))) unsigned int lds_u32;
typedef __attribute__((address_space(1))) const unsigned int glb_u32;
__device__ __forceinline__ void gl_lds16(const void* g, void* s) {
    __builtin_amdgcn_global_load_lds((glb_u32*)g, (lds_u32*)s, 16, 0, 0);
}

// ---- top-k: total order (val desc, idx asc) — matches jax.lax.top_k tie-break ----
__device__ __forceinline__ bool topgt(float a, int ia, float b, int ib) {
    return (a > b) || (a == b && ia < ib);
}
__device__ __forceinline__ void cexch(float& a, int& ia, float& b, int& ib) {
    bool c = topgt(a, ia, b, ib);
    float tv = c ? a : b; float tw = c ? b : a;
    int ti = c ? ia : ib; int tj = c ? ib : ia;
    a = tv; ia = ti; b = tw; ib = tj;
}
// insert (v,i) into sorted-desc-4 list (s,si)
__device__ __forceinline__ void insert4(float v, int i, float* s, int* si) {
    bool c = topgt(v, i, s[3], si[3]);
    s[3] = c ? v : s[3]; si[3] = c ? i : si[3];
    cexch(s[2], si[2], s[3], si[3]);
    cexch(s[1], si[1], s[2], si[2]);
    cexch(s[0], si[0], s[1], si[1]);
}

// ---------------- u_halt norms ----------------
__global__ void k_unorm(const float* __restrict__ u_halt, float* __restrict__ norm_inv) {
    __shared__ float red[256];
    int tid = threadIdx.x;
    for (int h = 0; h < HH; ++h) {
        float s = 0.f;
        for (int i = tid; i < FF; i += 256) { float v = u_halt[h * FF + i]; s += v * v; }
        red[tid] = s; __syncthreads();
        for (int off = 128; off > 0; off >>= 1) {
            if (tid < off) red[tid] += red[tid + off];
            __syncthreads();
        }
        if (tid == 0) norm_inv[h] = 1.0f / sqrtf(red[0] + EPSV);
        __syncthreads();
    }
}

// ---------------- fp32 -> bf16 cast ----------------
__global__ void k_cvt_bf(const float* __restrict__ in, ushort_t* __restrict__ out, int total) {
    int i = blockIdx.x * 256 + threadIdx.x;
    if (i >= total) return;
    out[i] = f2bf(in[i]);
}

// ---------------- GEMM + online softmax/top-4 partials ----------------
// grid (NG, BT/RB). Per (row, group) writes 12 floats: [m, Z, v0..3, bits(i0..3)],
// i = within-head column index.
__global__ __launch_bounds__(256) void k_gemm_topk(const ushort_t* __restrict__ A,
                                                   const ushort_t* __restrict__ B,
                                                   float* __restrict__ pbuf) {
    __shared__ __align__(16) ushort_t As[RB * BKE];        // 4 KB
    __shared__ __align__(16) ushort_t Bs[CTILE * BKE];     // 8 KB
    __shared__ float Sc[RB][CTILE + 5];                    // 34 KB, stride 133 (2-way banks, free)

    int tid = threadIdx.x;
    int lane = tid & 63, w = tid >> 6;
    int g = blockIdx.x;
    int row0 = blockIdx.y * RB;

    // per-row running state, registers of thread r (= tid) for tid < RB
    float rm = -1e30f, rz = 0.f;
    float rv[4] = {-1e30f, -1e30f, -1e30f, -1e30f};
    int   ri[4] = {0x7FFFFFFF, 0x7FFFFFFF, 0x7FFFFFFF, 0x7FFFFFFF};

    int achk = (lane & 3) * 8;
    const ushort_t* gA = A + (size_t)(row0 + w * 16 + (lane >> 2)) * FF + achk;
    ushort_t* sA  = As + (w * 16) * BKE;           // wave-uniform; HW adds lane*16B
    ushort_t* sB0 = Bs + (w * 16) * BKE;
    ushort_t* sB1 = Bs + (64 + w * 16) * BKE;

    int rw = (w >> 1) * 32;    // wave row offset
    int cw = (w & 1) * 64;     // wave col offset
    int fr = lane & 15;
    int fk = (lane >> 4) * 8;
    int crow = (lane >> 4) * 4;

    for (int ct = 0; ct < GW / CTILE; ct++) {
        const ushort_t* gB = B + (size_t)(g * GW + ct * CTILE + w * 16 + (lane >> 2)) * FF + achk;
        f32x4 acc[2][4] = {};
        for (int kb = 0; kb < FF; kb += BKE) {
            gl_lds16(gA + kb, sA);
            gl_lds16(gB + kb, sB0);
            gl_lds16(gB + kb + (size_t)64 * FF, sB1);
            __syncthreads();
            bf16x8 af[2], bfv[4];
            af[0] = *(const bf16x8*)&As[(rw + fr) * BKE + fk];
            af[1] = *(const bf16x8*)&As[(rw + 16 + fr) * BKE + fk];
            #pragma unroll
            for (int j = 0; j < 4; j++) bfv[j] = *(const bf16x8*)&Bs[(cw + 16 * j + fr) * BKE + fk];
            #pragma unroll
            for (int i = 0; i < 2; i++)
                #pragma unroll
                for (int j = 0; j < 4; j++)
                    acc[i][j] = __builtin_amdgcn_mfma_f32_16x16x32_bf16(af[i], bfv[j], acc[i][j], 0, 0, 0);
            __syncthreads();
        }
        // dump tile to LDS (C layout: col=lane&15, row=(lane>>4)*4+reg)
        #pragma unroll
        for (int i = 0; i < 2; i++)
            #pragma unroll
            for (int j = 0; j < 4; j++)
                #pragma unroll
                for (int r = 0; r < 4; r++)
                    Sc[rw + 16 * i + crow + r][cw + 16 * j + fr] = acc[i][j][r];
        __syncthreads();

        // scan: thread r (< RB) sweeps its full row
        if (tid < RB) {
            const float* row = &Sc[tid][0];
            float tv[4] = {-1e30f, -1e30f, -1e30f, -1e30f};
            int   ti[4] = {0x7FFFFFFF, 0x7FFFFFFF, 0x7FFFFFFF, 0x7FFFFFFF};
            int nb = (g & 1) * GW + ct * CTILE;
            for (int c = 0; c < CTILE; c++) insert4(row[c], nb + c, tv, ti);
            float m = tv[0];
            float Z = 0.f;
            for (int c = 0; c < CTILE; c++) Z += __expf(row[c] - m);
            float mn = fmaxf(rm, m);
            rz = rz * __expf(rm - mn) + Z * __expf(m - mn);
            rm = mn;
            insert4(tv[0], ti[0], rv, ri);
            insert4(tv[1], ti[1], rv, ri);
            insert4(tv[2], ti[2], rv, ri);
            insert4(tv[3], ti[3], rv, ri);
        }
        __syncthreads();
    }
    if (tid < RB) {
        float* pb = pbuf + ((size_t)(row0 + tid) * NG + g) * 12;
        pb[0] = rm; pb[1] = rz;
        #pragma unroll
        for (int k = 0; k < 4; k++) { pb[2 + k] = rv[k]; pb[6 + k] = __int_as_float(ri[k]); }
    }
}

// ---------------- fused stage2-merge + solve + halt + pool ----------------
__global__ __launch_bounds__(256) void k_fused(const float* __restrict__ psi,
                                               float* __restrict__ psi_h,
                                               const float* __restrict__ bank_vals,
                                               const float* __restrict__ pbuf,
                                               const float* __restrict__ u_halt,
                                               const float* __restrict__ norm_inv,
                                               const float* __restrict__ W_halt,
                                               const float* __restrict__ b_halt,
                                               const float* __restrict__ head_mix,
                                               float* __restrict__ merged,
                                               ushort_t* __restrict__ feat,
                                               float* __restrict__ cum,
                                               float* __restrict__ cost,
                                               int* __restrict__ halted,
                                               int first, int is_last) {
    __shared__ float Pn[HH][FF];
    __shared__ float xw[4][9];
    int b = blockIdx.x;
    int tid = threadIdx.x;
    int w = tid >> 6, lane = tid & 63;
    int bh = b * HH + w;

    // ---- merge the two col-group partials of this head ----
    const float* pb0 = pbuf + ((size_t)b * NG + 2 * w) * 12;
    float m0 = pb0[0], Z0 = pb0[1];
    float v0[4]; int i0[4];
    #pragma unroll
    for (int k = 0; k < 4; k++) { v0[k] = pb0[2 + k]; i0[k] = __float_as_int(pb0[6 + k]); }
    float m1 = pb0[12], Z1 = pb0[13];
    float mm = fmaxf(m0, m1);
    float Zt = Z0 * __expf(m0 - mm) + Z1 * __expf(m1 - mm);
    #pragma unroll
    for (int k = 0; k < 4; k++) insert4(pb0[14 + k], __float_as_int(pb0[18 + k]), v0, i0);
    float Zinv = 1.0f / Zt;
    float wk[KK]; int ix[KK];
    #pragma unroll
    for (int k = 0; k < KK; k++) { wk[k] = expf(v0[k] - mm) * Zinv; ix[k] = i0[k]; }

    const float* Pr = first ? (psi + (size_t)b * FF) : (psi_h + (size_t)bh * FF);
    float4 p4[4], v4[KK][4];
    #pragma unroll
    for (int c = 0; c < 4; c++) p4[c] = *(const float4*)(Pr + lane * 16 + 4 * c);
    #pragma unroll
    for (int k = 0; k < KK; k++) {
        const float* Vp = bank_vals + ((size_t)(w * NN) + ix[k]) * FF + lane * 16;
        #pragma unroll
        for (int c = 0; c < 4; c++) v4[k][c] = *(const float4*)(Vp + 4 * c);
    }

    float part[24];
    #pragma unroll
    for (int t = 0; t < 24; t++) part[t] = 0.f;
    #pragma unroll
    for (int c = 0; c < 4; c++) {
        #pragma unroll
        for (int e = 0; e < 2; e++) {
            float prr = e ? p4[c].z : p4[c].x;
            float pii = e ? p4[c].w : p4[c].y;
            float vr[KK], vi[KK];
            #pragma unroll
            for (int k = 0; k < KK; k++) {
                vr[k] = e ? v4[k][c].z : v4[k][c].x;
                vi[k] = e ? v4[k][c].w : v4[k][c].y;
            }
            #pragma unroll
            for (int k = 0; k < KK; k++) {
                part[2 * k]     += vr[k] * prr + vi[k] * pii;
                part[2 * k + 1] += vr[k] * pii - vi[k] * prr;
                part[8 + k]     += vr[k] * vr[k] + vi[k] * vi[k];
            }
            int t = 12;
            #pragma unroll
            for (int k = 0; k < KK; k++)
                #pragma unroll
                for (int j = k + 1; j < KK; j++) {
                    part[t]     += vr[k] * vr[j] + vi[k] * vi[j];
                    part[t + 1] += vr[k] * vi[j] - vi[k] * vr[j];
                    t += 2;
                }
        }
    }
    #pragma unroll
    for (int m = 1; m < 64; m <<= 1)
        #pragma unroll
        for (int t = 0; t < 24; t++) part[t] += __shfl_xor(part[t], m, 64);

    float mr[KK], mi[KK], Gr[KK][KK], Gi[KK][KK];
    #pragma unroll
    for (int k = 0; k < KK; k++) {
        mr[k] = part[2 * k] * wk[k];
        mi[k] = part[2 * k + 1] * wk[k];
        Gr[k][k] = part[8 + k] * wk[k] * wk[k] + EPSV;
        Gi[k][k] = 0.f;
    }
    {
        int t = 12;
        #pragma unroll
        for (int k = 0; k < KK; k++)
            #pragma unroll
            for (int j = k + 1; j < KK; j++) {
                float s = wk[k] * wk[j];
                Gr[k][j] = part[t] * s;  Gi[k][j] = part[t + 1] * s;
                Gr[j][k] = Gr[k][j];     Gi[j][k] = -Gi[k][j];
                t += 2;
            }
    }

    float Lr[KK][KK], Li[KK][KK];
    #pragma unroll
    for (int j = 0; j < KK; j++) {
        float s = Gr[j][j];
        #pragma unroll
        for (int p = 0; p < KK; p++) if (p < j) s -= Lr[j][p] * Lr[j][p] + Li[j][p] * Li[j][p];
        float ljj = sqrtf(fmaxf(s, 1e-30f));
        Lr[j][j] = ljj; Li[j][j] = 0.f;
        float inv = 1.0f / ljj;
        #pragma unroll
        for (int k = 0; k < KK; k++) {
            if (k > j) {
                float ar = Gr[k][j], ai = Gi[k][j];
                #pragma unroll
                for (int p = 0; p < KK; p++) if (p < j) {
                    ar -= Lr[k][p] * Lr[j][p] + Li[k][p] * Li[j][p];
                    ai -= Li[k][p] * Lr[j][p] - Lr[k][p] * Li[j][p];
                }
                Lr[k][j] = ar * inv; Li[k][j] = ai * inv;
            }
        }
    }
    float yr[KK], yi[KK];
    #pragma unroll
    for (int j = 0; j < KK; j++) {
        float ar = mr[j], ai = mi[j];
        #pragma unroll
        for (int p = 0; p < KK; p++) if (p < j) {
            ar -= Lr[j][p] * yr[p] - Li[j][p] * yi[p];
            ai -= Lr[j][p] * yi[p] + Li[j][p] * yr[p];
        }
        float inv = 1.0f / Lr[j][j];
        yr[j] = ar * inv; yi[j] = ai * inv;
    }
    float xr[KK], xi2[KK];
    #pragma unroll
    for (int j = KK - 1; j >= 0; j--) {
        float ar = yr[j], ai = yi[j];
        #pragma unroll
        for (int p = 0; p < KK; p++) if (p > j) {
            ar -= Lr[p][j] * xr[p] + Li[p][j] * xi2[p];
            ai -= Lr[p][j] * xi2[p] - Li[p][j] * xr[p];
        }
        float inv = 1.0f / Lr[j][j];
        xr[j] = ar * inv; xi2[j] = ai * inv;
    }
    float cxr[KK], cxi[KK];
    #pragma unroll
    for (int k = 0; k < KK; k++) { cxr[k] = xr[k] * wk[k]; cxi[k] = xi2[k] * wk[k]; }

    float4 pj[4];
    float sqp = 0.f;
    #pragma unroll
    for (int c = 0; c < 4; c++) {
        float ar0 = 0.f, ai0 = 0.f, ar1 = 0.f, ai1 = 0.f;
        #pragma unroll
        for (int k = 0; k < KK; k++) {
            ar0 += v4[k][c].x * cxr[k] - v4[k][c].y * cxi[k];
            ai0 += v4[k][c].x * cxi[k] + v4[k][c].y * cxr[k];
            ar1 += v4[k][c].z * cxr[k] - v4[k][c].w * cxi[k];
            ai1 += v4[k][c].z * cxi[k] + v4[k][c].w * cxr[k];
        }
        pj[c].x = ar0; pj[c].y = ai0; pj[c].z = ar1; pj[c].w = ai1;
        sqp += ar0 * ar0 + ai0 * ai0 + ar1 * ar1 + ai1 * ai1;
    }
    #pragma unroll
    for (int m = 1; m < 64; m <<= 1) sqp += __shfl_xor(sqp, m, 64);
    float rn = 1.0f / sqrtf(fmaxf(sqp, 1e-6f));

    float* Pdst = psi_h + (size_t)bh * FF + lane * 16;
    #pragma unroll
    for (int c = 0; c < 4; c++) {
        float4 o; o.x = pj[c].x * rn; o.y = pj[c].y * rn; o.z = pj[c].z * rn; o.w = pj[c].w * rn;
        *(float4*)(Pdst + 4 * c) = o;
        *(float4*)&Pn[w][lane * 16 + 4 * c] = o;
    }
    __syncthreads();

    // ---------- halt phase ----------
    int t4 = tid * 4;
    float4 a0 = *(const float4*)&Pn[0][t4];
    float4 a1 = *(const float4*)&Pn[1][t4];
    float4 a2 = *(const float4*)&Pn[2][t4];
    float4 a3 = *(const float4*)&Pn[3][t4];
    float4 pool;
    pool.x = 0.25f * (a0.x + a1.x + a2.x + a3.x);
    pool.y = 0.25f * (a0.y + a1.y + a2.y + a3.y);
    pool.z = 0.25f * (a0.z + a1.z + a2.z + a3.z);
    pool.w = 0.25f * (a0.w + a1.w + a2.w + a3.w);

    float pt[9];
    #pragma unroll
    for (int h = 0; h < HH; h++) {
        float4 u = *(const float4*)&u_halt[h * FF + t4];
        pt[2 * h]     = u.x * pool.x + u.y * pool.y + u.z * pool.z + u.w * pool.w;
        pt[2 * h + 1] = u.x * pool.y - u.y * pool.x + u.z * pool.w - u.w * pool.z;
    }
    pt[8] = pool.x * pool.x + pool.y * pool.y + pool.z * pool.z + pool.w * pool.w;
    #pragma unroll
    for (int m = 1; m < 64; m <<= 1)
        #pragma unroll
        for (int t = 0; t < 9; t++) pt[t] += __shfl_xor(pt[t], m, 64);
    if (lane == 0) {
        #pragma unroll
        for (int t = 0; t < 9; t++) xw[w][t] = pt[t];
    }
    __syncthreads();
    float red[9];
    #pragma unroll
    for (int t = 0; t < 9; t++) red[t] = xw[0][t] + xw[1][t] + xw[2][t] + xw[3][t];
    float ns = red[8] + EPSV;

    float hm0 = head_mix[0], hm1 = head_mix[1], hm2 = head_mix[2], hm3 = head_mix[3];
    float hmx = fmaxf(fmaxf(hm0, hm1), fmaxf(hm2, hm3));
    float he[4] = {expf(hm0 - hmx), expf(hm1 - hmx), expf(hm2 - hmx), expf(hm3 - hmx)};
    float hsum = he[0] + he[1] + he[2] + he[3];

    float wgt[4], addc[4], newcum[4]; int newhl[4];
    int idxb = b * HH;
    #pragma unroll
    for (int h = 0; h < HH; h++) {
        float cr = red[2 * h] * norm_inv[h], ci = red[2 * h + 1] * norm_inv[h];
        float alpha = (cr * cr + ci * ci) / ns;
        float beta = 1.0f - alpha;
        float gamma = cr * cr / ns;
        float lg[3];
        #pragma unroll
        for (int j = 0; j < 3; j++)
            lg[j] = alpha * W_halt[(h * 3 + 0) * 3 + j] + beta * W_halt[(h * 3 + 1) * 3 + j] +
                    gamma * W_halt[(h * 3 + 2) * 3 + j] + b_halt[h * 3 + j];
        float mx = fmaxf(lg[0], fmaxf(lg[1], lg[2]));
        float e0 = expf(lg[0] - mx), e1 = expf(lg[1] - mx), e2 = expf(lg[2] - mx);
        float p_halt = (e0 + e1) / (e0 + e1 + e2);
        float cm = cum[idxb + h];
        int hl = halted[idxb + h];
        float would = cm + p_halt;
        int halts_now = (would >= THRESHV) || is_last;
        int active = hl ? 0 : 1;
        wgt[h]  = active ? (halts_now ? (1.0f - cm) : p_halt) : 0.0f;
        addc[h] = active ? p_halt : 0.0f;
        newcum[h] = (active && !halts_now) ? would : cm;
        newhl[h]  = hl || (active && halts_now);
    }
    __syncthreads();
    if (tid < HH) {
        cost[idxb + tid] += addc[tid];
        cum[idxb + tid] = newcum[tid];
        halted[idxb + tid] = newhl[tid];
    }
    float hwv[4];
    #pragma unroll
    for (int h = 0; h < HH; h++) hwv[h] = (he[h] / hsum) * wgt[h];

    size_t mo = (size_t)b * FF + t4;
    float4 m4 = *(const float4*)&merged[mo];
    m4.x += hwv[0] * a0.x + hwv[1] * a1.x + hwv[2] * a2.x + hwv[3] * a3.x;
    m4.y += hwv[0] * a0.y + hwv[1] * a1.y + hwv[2] * a2.y + hwv[3] * a3.y;
    m4.z += hwv[0] * a0.z + hwv[1] * a1.z + hwv[2] * a2.z + hwv[3] * a3.z;
    m4.w += hwv[0] * a0.w + hwv[1] * a1.w + hwv[2] * a2.w + hwv[3] * a3.w;
    *(float4*)&merged[mo] = m4;

    us4 fb;
    fb.x = f2bf(pool.x); fb.y = f2bf(pool.y); fb.z = f2bf(pool.z); fb.w = f2bf(pool.w);
    *(us4*)&feat[mo] = fb;
}

// ---------------- final output ----------------
__global__ void k_out(const float* __restrict__ psi, const float* __restrict__ merged,
                      const float* __restrict__ out_scale, float* __restrict__ out, int total) {
    int i = blockIdx.x * 256 + threadIdx.x;
    if (i >= total) return;
    float p = psi[i];
    out[i] = p + out_scale[0] * (merged[i] - p);
}

__global__ void k_costmean(const float* __restrict__ cost, float* __restrict__ out, int n) {
    __shared__ float red[256];
    int tid = threadIdx.x;
    float s = 0.f;
    for (int i = tid; i < n; i += 256) s += cost[i];
    red[tid] = s; __syncthreads();
    for (int off = 128; off > 0; off >>= 1) {
        if (tid < off) red[tid] += red[tid + off];
        __syncthreads();
    }
    if (tid == 0) out[0] = red[0] / (float)n;
}

extern "C" void kernel_launch(void* const* d_in, const int* in_sizes, int n_in,
                              void* d_out, int out_size, void* d_ws, size_t ws_size,
                              hipStream_t stream) {
    const float* psi       = (const float*)d_in[0];
    const float* bank_keys = (const float*)d_in[1];
    const float* bank_vals = (const float*)d_in[2];
    const float* u_halt    = (const float*)d_in[3];
    const float* W_halt    = (const float*)d_in[4];
    const float* b_halt    = (const float*)d_in[5];
    const float* head_mix  = (const float*)d_in[6];
    const float* out_scale = (const float*)d_in[7];
    float* out = (float*)d_out;

    const int BT = in_sizes[0] / FF;    // 4096

    float* ws = (float*)d_ws;
    size_t off = 0;
    float* psi_h  = ws + off; off += (size_t)BT * HH * FF;
    float* merged = ws + off; off += (size_t)BT * FF;     // zero region starts here
    float* cum    = ws + off; off += (size_t)BT * HH;
    float* costv  = ws + off; off += (size_t)BT * HH;
    int*   halted = (int*)(ws + off); off += (size_t)BT * HH;
    float* norminv = ws + off; off += 16;
    float* pbuf   = ws + off; off += (size_t)BT * NG * 12;
    ushort_t* feat_bf = (ushort_t*)(ws + off); off += (size_t)BT * FF / 2;
    ushort_t* keys_bf = (ushort_t*)(ws + off); off += (size_t)HH * NN * FF / 2;

    hipMemsetAsync(merged, 0, ((size_t)BT * FF + 3 * (size_t)BT * HH) * sizeof(float), stream);
    k_unorm<<<1, 256, 0, stream>>>(u_halt, norminv);
    int tot_keys = HH * NN * FF;
    k_cvt_bf<<<(tot_keys + 255) / 256, 256, 0, stream>>>(bank_keys, keys_bf, tot_keys);
    int tot_bf = BT * FF;
    k_cvt_bf<<<(tot_bf + 255) / 256, 256, 0, stream>>>(psi, feat_bf, tot_bf);  // iter-0 feat = psi

    for (int it = 0; it < TMAXI; ++it) {
        k_gemm_topk<<<dim3(NG, BT / RB), 256, 0, stream>>>(feat_bf, keys_bf, pbuf);
        k_fused<<<BT, 256, 0, stream>>>(psi, psi_h, bank_vals, pbuf, u_halt, norminv,
                                        W_halt, b_halt, head_mix, merged, feat_bf,
                                        cum, costv, halted,
                                        (it == 0) ? 1 : 0, (it == TMAXI - 1) ? 1 : 0);
    }
    k_out<<<(tot_bf + 255) / 256, 256, 0, stream>>>(psi, merged, out_scale, out, tot_bf);
    k_costmean<<<1, 256, 0, stream>>>(costv, out + tot_bf, BT * HH);
}

// Round 7
// 1578.362 us; speedup vs baseline: 1.2345x; 1.2345x over previous
//
#include <hip/hip_runtime.h>
#include <math.h>

#define HH 4
#define FF 1024          // 2*d floats per complex vector
#define NN 2048
#define KK 4
#define TMAXI 4
#define THRESHV 0.99f
#define EPSV 1e-6f
#define NCB 64           // col-blocks of 128 over 8192 cols (16 per head)
#define BKE 32           // K-chunk elems
#define SCP 129          // Sc stride: 129 % 32 == 1 -> conflict-free row scan

typedef unsigned short ushort_t;
typedef __attribute__((ext_vector_type(8))) __bf16 bf16x8;
typedef __attribute__((ext_vector_type(4))) float f32x4;
typedef __attribute__((ext_vector_type(4))) unsigned short us4;

__device__ __forceinline__ unsigned short f2bf(float x) {
    unsigned int u = __float_as_uint(x);
    unsigned int r = (u + 0x7FFF + ((u >> 16) & 1)) >> 16;
    return (unsigned short)r;
}

typedef __attribute__((address_space(3))) unsigned int lds_u32;
typedef __attribute__((address_space(1))) const unsigned int glb_u32;
__device__ __forceinline__ void gl_lds16(const void* g, void* s) {
    __builtin_amdgcn_global_load_lds((glb_u32*)g, (lds_u32*)s, 16, 0, 0);
}

// ---- top-k: total order (val desc, idx asc) — matches jax.lax.top_k tie-break ----
__device__ __forceinline__ bool topgt(float a, int ia, float b, int ib) {
    return (a > b) || (a == b && ia < ib);
}
__device__ __forceinline__ void cexch(float& a, int& ia, float& b, int& ib) {
    bool c = topgt(a, ia, b, ib);
    float tv = c ? a : b; float tw = c ? b : a;
    int ti = c ? ia : ib; int tj = c ? ib : ia;
    a = tv; ia = ti; b = tw; ib = tj;
}
// insert (v,i) into sorted-desc-4 list (s,si)
__device__ __forceinline__ void insert4(float v, int i, float* s, int* si) {
    bool c = topgt(v, i, s[3], si[3]);
    s[3] = c ? v : s[3]; si[3] = c ? i : si[3];
    cexch(s[2], si[2], s[3], si[3]);
    cexch(s[1], si[1], s[2], si[2]);
    cexch(s[0], si[0], s[1], si[1]);
}

// ---------------- u_halt norms ----------------
__global__ void k_unorm(const float* __restrict__ u_halt, float* __restrict__ norm_inv) {
    __shared__ float red[256];
    int tid = threadIdx.x;
    for (int h = 0; h < HH; ++h) {
        float s = 0.f;
        for (int i = tid; i < FF; i += 256) { float v = u_halt[h * FF + i]; s += v * v; }
        red[tid] = s; __syncthreads();
        for (int off = 128; off > 0; off >>= 1) {
            if (tid < off) red[tid] += red[tid + off];
            __syncthreads();
        }
        if (tid == 0) norm_inv[h] = 1.0f / sqrtf(red[0] + EPSV);
        __syncthreads();
    }
}

// ---------------- fp32 -> bf16 cast ----------------
__global__ void k_cvt_bf(const float* __restrict__ in, ushort_t* __restrict__ out, int total) {
    int i = blockIdx.x * 256 + threadIdx.x;
    if (i >= total) return;
    out[i] = f2bf(in[i]);
}

// ---------------- 128x128 MFMA GEMM tile + softmax/top-4 partial epilogue ----------------
// grid (NCB, BT/128). Per (row, col-block) writes 10 floats:
// [m, Z, v0..3, bits(i0..3)], i = within-head column index. pbuf stride 12.
__global__ __launch_bounds__(256) void k_gemm_topk(const ushort_t* __restrict__ A,
                                                   const ushort_t* __restrict__ B,
                                                   float* __restrict__ pbuf) {
    // union: K-loop staging (16 KB) overlaps score tile (66 KB)
    __shared__ __align__(16) char smem[128 * SCP * 4];
    ushort_t* As = (ushort_t*)smem;            // 128*32 bf16 = 8 KB
    ushort_t* Bs = As + 128 * BKE;             // 8 KB
    float* Sc = (float*)smem;                  // 128 x 129 fp32, after K-loop

    int tid = threadIdx.x;
    int lane = tid & 63, w = tid >> 6;
    int cb = blockIdx.x;
    int row0 = blockIdx.y * 128;
    int col0 = cb * 128;

    const ushort_t* gA = A + (size_t)(row0 + w * 16 + (lane >> 2)) * FF + (lane & 3) * 8;
    const ushort_t* gB = B + (size_t)(col0 + w * 16 + (lane >> 2)) * FF + (lane & 3) * 8;
    ushort_t* sA = As + (w * 16) * BKE;        // wave-uniform base; HW adds lane*16B
    ushort_t* sB = Bs + (w * 16) * BKE;

    int fr = lane & 15;
    int fk = (lane >> 4) * 8;
    int wr0 = (w >> 1) * 64, wc0 = (w & 1) * 64;

    f32x4 acc[4][4] = {};
    for (int kb = 0; kb < FF; kb += BKE) {
        gl_lds16(gA + kb, sA);
        gl_lds16(gA + kb + (size_t)64 * FF, sA + 64 * BKE);
        gl_lds16(gB + kb, sB);
        gl_lds16(gB + kb + (size_t)64 * FF, sB + 64 * BKE);
        __syncthreads();
        bf16x8 af[4], bfv[4];
        #pragma unroll
        for (int i = 0; i < 4; i++) af[i] = *(const bf16x8*)&As[(wr0 + 16 * i + fr) * BKE + fk];
        #pragma unroll
        for (int j = 0; j < 4; j++) bfv[j] = *(const bf16x8*)&Bs[(wc0 + 16 * j + fr) * BKE + fk];
        #pragma unroll
        for (int i = 0; i < 4; i++)
            #pragma unroll
            for (int j = 0; j < 4; j++)
                acc[i][j] = __builtin_amdgcn_mfma_f32_16x16x32_bf16(af[i], bfv[j], acc[i][j], 0, 0, 0);
        __syncthreads();   // after this barrier of the LAST iter, As/Bs are dead -> Sc may alias
    }

    // dump acc to Sc (C layout: col=lane&15, row=(lane>>4)*4+reg)
    int crow = (lane >> 4) * 4;
    #pragma unroll
    for (int i = 0; i < 4; i++)
        #pragma unroll
        for (int j = 0; j < 4; j++)
            #pragma unroll
            for (int r = 0; r < 4; r++)
                Sc[(wr0 + 16 * i + crow + r) * SCP + wc0 + 16 * j + fr] = acc[i][j][r];
    __syncthreads();

    // scan: thread t -> row t>>1, col half (t&1)*64 .. +63. addr%32 = (row+c)%32 -> 2-way, free
    int srow = tid >> 1, seg = tid & 1;
    const float* rowp = Sc + srow * SCP + seg * 64;
    float rv[4] = {-1e30f, -1e30f, -1e30f, -1e30f};
    int   ri[4] = {0x7FFFFFFF, 0x7FFFFFFF, 0x7FFFFFFF, 0x7FFFFFFF};
    int nb = (cb & 15) * 128 + seg * 64;       // within-head column base
    for (int c = 0; c < 64; c++) insert4(rowp[c], nb + c, rv, ri);
    float m = rv[0];
    float Z = 0.f;
    for (int c = 0; c < 64; c++) Z += __expf(rowp[c] - m);

    // pairwise merge with neighbor lane (scalar shfls only)
    float om = __shfl_xor(m, 1, 64);
    float oZ = __shfl_xor(Z, 1, 64);
    float w0 = __shfl_xor(rv[0], 1, 64);
    float w1 = __shfl_xor(rv[1], 1, 64);
    float w2 = __shfl_xor(rv[2], 1, 64);
    float w3 = __shfl_xor(rv[3], 1, 64);
    int j0 = __shfl_xor(ri[0], 1, 64);
    int j1 = __shfl_xor(ri[1], 1, 64);
    int j2 = __shfl_xor(ri[2], 1, 64);
    int j3 = __shfl_xor(ri[3], 1, 64);
    float mn = fmaxf(m, om);
    float Zm = Z * __expf(m - mn) + oZ * __expf(om - mn);
    insert4(w0, j0, rv, ri);
    insert4(w1, j1, rv, ri);
    insert4(w2, j2, rv, ri);
    insert4(w3, j3, rv, ri);
    if (seg == 0) {
        float* pb = pbuf + ((size_t)(row0 + srow) * NCB + cb) * 12;
        pb[0] = mn; pb[1] = Zm;
        #pragma unroll
        for (int k = 0; k < 4; k++) { pb[2 + k] = rv[k]; pb[6 + k] = __int_as_float(ri[k]); }
    }
}

// ---------------- fused 16-partial merge + solve + halt + pool ----------------
__global__ __launch_bounds__(256) void k_fused(const float* __restrict__ psi,
                                               float* __restrict__ psi_h,
                                               const float* __restrict__ bank_vals,
                                               const float* __restrict__ pbuf,
                                               const float* __restrict__ u_halt,
                                               const float* __restrict__ norm_inv,
                                               const float* __restrict__ W_halt,
                                               const float* __restrict__ b_halt,
                                               const float* __restrict__ head_mix,
                                               float* __restrict__ merged,
                                               ushort_t* __restrict__ feat,
                                               float* __restrict__ cum,
                                               float* __restrict__ cost,
                                               int* __restrict__ halted,
                                               int first, int is_last) {
    __shared__ float Pn[HH][FF];
    __shared__ float xw[4][9];
    int b = blockIdx.x;
    int tid = threadIdx.x;
    int w = tid >> 6, lane = tid & 63;
    int bh = b * HH + w;

    // ---- merge the 16 col-block partials of this head (all lanes redundant) ----
    const float* base = pbuf + ((size_t)b * NCB + w * 16) * 12;
    float mm = base[0], Zt = base[1];
    float v0[4]; int i0[4];
    #pragma unroll
    for (int k = 0; k < 4; k++) { v0[k] = base[2 + k]; i0[k] = __float_as_int(base[6 + k]); }
    for (int t = 1; t < 16; t++) {
        const float* q = base + t * 12;
        float m1 = q[0], Z1 = q[1];
        float mn = fmaxf(mm, m1);
        Zt = Zt * __expf(mm - mn) + Z1 * __expf(m1 - mn);
        mm = mn;
        insert4(q[2], __float_as_int(q[6]), v0, i0);
        insert4(q[3], __float_as_int(q[7]), v0, i0);
        insert4(q[4], __float_as_int(q[8]), v0, i0);
        insert4(q[5], __float_as_int(q[9]), v0, i0);
    }
    float Zinv = 1.0f / Zt;
    float wk[KK]; int ix[KK];
    #pragma unroll
    for (int k = 0; k < KK; k++) { wk[k] = expf(v0[k] - mm) * Zinv; ix[k] = i0[k]; }

    const float* Pr = first ? (psi + (size_t)b * FF) : (psi_h + (size_t)bh * FF);
    float4 p4[4], v4[KK][4];
    #pragma unroll
    for (int c = 0; c < 4; c++) p4[c] = *(const float4*)(Pr + lane * 16 + 4 * c);
    #pragma unroll
    for (int k = 0; k < KK; k++) {
        const float* Vp = bank_vals + ((size_t)(w * NN) + ix[k]) * FF + lane * 16;
        #pragma unroll
        for (int c = 0; c < 4; c++) v4[k][c] = *(const float4*)(Vp + 4 * c);
    }

    float part[24];
    #pragma unroll
    for (int t = 0; t < 24; t++) part[t] = 0.f;
    #pragma unroll
    for (int c = 0; c < 4; c++) {
        #pragma unroll
        for (int e = 0; e < 2; e++) {
            float prr = e ? p4[c].z : p4[c].x;
            float pii = e ? p4[c].w : p4[c].y;
            float vr[KK], vi[KK];
            #pragma unroll
            for (int k = 0; k < KK; k++) {
                vr[k] = e ? v4[k][c].z : v4[k][c].x;
                vi[k] = e ? v4[k][c].w : v4[k][c].y;
            }
            #pragma unroll
            for (int k = 0; k < KK; k++) {
                part[2 * k]     += vr[k] * prr + vi[k] * pii;
                part[2 * k + 1] += vr[k] * pii - vi[k] * prr;
                part[8 + k]     += vr[k] * vr[k] + vi[k] * vi[k];
            }
            int t = 12;
            #pragma unroll
            for (int k = 0; k < KK; k++)
                #pragma unroll
                for (int j = k + 1; j < KK; j++) {
                    part[t]     += vr[k] * vr[j] + vi[k] * vi[j];
                    part[t + 1] += vr[k] * vi[j] - vi[k] * vr[j];
                    t += 2;
                }
        }
    }
    #pragma unroll
    for (int m = 1; m < 64; m <<= 1)
        #pragma unroll
        for (int t = 0; t < 24; t++) part[t] += __shfl_xor(part[t], m, 64);

    float mr[KK], mi[KK], Gr[KK][KK], Gi[KK][KK];
    #pragma unroll
    for (int k = 0; k < KK; k++) {
        mr[k] = part[2 * k] * wk[k];
        mi[k] = part[2 * k + 1] * wk[k];
        Gr[k][k] = part[8 + k] * wk[k] * wk[k] + EPSV;
        Gi[k][k] = 0.f;
    }
    {
        int t = 12;
        #pragma unroll
        for (int k = 0; k < KK; k++)
            #pragma unroll
            for (int j = k + 1; j < KK; j++) {
                float s = wk[k] * wk[j];
                Gr[k][j] = part[t] * s;  Gi[k][j] = part[t + 1] * s;
                Gr[j][k] = Gr[k][j];     Gi[j][k] = -Gi[k][j];
                t += 2;
            }
    }

    float Lr[KK][KK], Li[KK][KK];
    #pragma unroll
    for (int j = 0; j < KK; j++) {
        float s = Gr[j][j];
        #pragma unroll
        for (int p = 0; p < KK; p++) if (p < j) s -= Lr[j][p] * Lr[j][p] + Li[j][p] * Li[j][p];
        float ljj = sqrtf(fmaxf(s, 1e-30f));
        Lr[j][j] = ljj; Li[j][j] = 0.f;
        float inv = 1.0f / ljj;
        #pragma unroll
        for (int k = 0; k < KK; k++) {
            if (k > j) {
                float ar = Gr[k][j], ai = Gi[k][j];
                #pragma unroll
                for (int p = 0; p < KK; p++) if (p < j) {
                    ar -= Lr[k][p] * Lr[j][p] + Li[k][p] * Li[j][p];
                    ai -= Li[k][p] * Lr[j][p] - Lr[k][p] * Li[j][p];
                }
                Lr[k][j] = ar * inv; Li[k][j] = ai * inv;
            }
        }
    }
    float yr[KK], yi[KK];
    #pragma unroll
    for (int j = 0; j < KK; j++) {
        float ar = mr[j], ai = mi[j];
        #pragma unroll
        for (int p = 0; p < KK; p++) if (p < j) {
            ar -= Lr[j][p] * yr[p] - Li[j][p] * yi[p];
            ai -= Lr[j][p] * yi[p] + Li[j][p] * yr[p];
        }
        float inv = 1.0f / Lr[j][j];
        yr[j] = ar * inv; yi[j] = ai * inv;
    }
    float xr[KK], xi2[KK];
    #pragma unroll
    for (int j = KK - 1; j >= 0; j--) {
        float ar = yr[j], ai = yi[j];
        #pragma unroll
        for (int p = 0; p < KK; p++) if (p > j) {
            ar -= Lr[p][j] * xr[p] + Li[p][j] * xi2[p];
            ai -= Lr[p][j] * xi2[p] - Li[p][j] * xr[p];
        }
        float inv = 1.0f / Lr[j][j];
        xr[j] = ar * inv; xi2[j] = ai * inv;
    }
    float cxr[KK], cxi[KK];
    #pragma unroll
    for (int k = 0; k < KK; k++) { cxr[k] = xr[k] * wk[k]; cxi[k] = xi2[k] * wk[k]; }

    float4 pj[4];
    float sqp = 0.f;
    #pragma unroll
    for (int c = 0; c < 4; c++) {
        float ar0 = 0.f, ai0 = 0.f, ar1 = 0.f, ai1 = 0.f;
        #pragma unroll
        for (int k = 0; k < KK; k++) {
            ar0 += v4[k][c].x * cxr[k] - v4[k][c].y * cxi[k];
            ai0 += v4[k][c].x * cxi[k] + v4[k][c].y * cxr[k];
            ar1 += v4[k][c].z * cxr[k] - v4[k][c].w * cxi[k];
            ai1 += v4[k][c].z * cxi[k] + v4[k][c].w * cxr[k];
        }
        pj[c].x = ar0; pj[c].y = ai0; pj[c].z = ar1; pj[c].w = ai1;
        sqp += ar0 * ar0 + ai0 * ai0 + ar1 * ar1 + ai1 * ai1;
    }
    #pragma unroll
    for (int m = 1; m < 64; m <<= 1) sqp += __shfl_xor(sqp, m, 64);
    float rn = 1.0f / sqrtf(fmaxf(sqp, 1e-6f));

    float* Pdst = psi_h + (size_t)bh * FF + lane * 16;
    #pragma unroll
    for (int c = 0; c < 4; c++) {
        float4 o; o.x = pj[c].x * rn; o.y = pj[c].y * rn; o.z = pj[c].z * rn; o.w = pj[c].w * rn;
        *(float4*)(Pdst + 4 * c) = o;
        *(float4*)&Pn[w][lane * 16 + 4 * c] = o;
    }
    __syncthreads();

    // ---------- halt phase ----------
    int t4 = tid * 4;
    float4 a0 = *(const float4*)&Pn[0][t4];
    float4 a1 = *(const float4*)&Pn[1][t4];
    float4 a2 = *(const float4*)&Pn[2][t4];
    float4 a3 = *(const float4*)&Pn[3][t4];
    float4 pool;
    pool.x = 0.25f * (a0.x + a1.x + a2.x + a3.x);
    pool.y = 0.25f * (a0.y + a1.y + a2.y + a3.y);
    pool.z = 0.25f * (a0.z + a1.z + a2.z + a3.z);
    pool.w = 0.25f * (a0.w + a1.w + a2.w + a3.w);

    float pt[9];
    #pragma unroll
    for (int h = 0; h < HH; h++) {
        float4 u = *(const float4*)&u_halt[h * FF + t4];
        pt[2 * h]     = u.x * pool.x + u.y * pool.y + u.z * pool.z + u.w * pool.w;
        pt[2 * h + 1] = u.x * pool.y - u.y * pool.x + u.z * pool.w - u.w * pool.z;
    }
    pt[8] = pool.x * pool.x + pool.y * pool.y + pool.z * pool.z + pool.w * pool.w;
    #pragma unroll
    for (int m = 1; m < 64; m <<= 1)
        #pragma unroll
        for (int t = 0; t < 9; t++) pt[t] += __shfl_xor(pt[t], m, 64);
    if (lane == 0) {
        #pragma unroll
        for (int t = 0; t < 9; t++) xw[w][t] = pt[t];
    }
    __syncthreads();
    float red[9];
    #pragma unroll
    for (int t = 0; t < 9; t++) red[t] = xw[0][t] + xw[1][t] + xw[2][t] + xw[3][t];
    float ns = red[8] + EPSV;

    float hm0 = head_mix[0], hm1 = head_mix[1], hm2 = head_mix[2], hm3 = head_mix[3];
    float hmx = fmaxf(fmaxf(hm0, hm1), fmaxf(hm2, hm3));
    float he[4] = {expf(hm0 - hmx), expf(hm1 - hmx), expf(hm2 - hmx), expf(hm3 - hmx)};
    float hsum = he[0] + he[1] + he[2] + he[3];

    float wgt[4], addc[4], newcum[4]; int newhl[4];
    int idxb = b * HH;
    #pragma unroll
    for (int h = 0; h < HH; h++) {
        float cr = red[2 * h] * norm_inv[h], ci = red[2 * h + 1] * norm_inv[h];
        float alpha = (cr * cr + ci * ci) / ns;
        float beta = 1.0f - alpha;
        float gamma = cr * cr / ns;
        float lg[3];
        #pragma unroll
        for (int j = 0; j < 3; j++)
            lg[j] = alpha * W_halt[(h * 3 + 0) * 3 + j] + beta * W_halt[(h * 3 + 1) * 3 + j] +
                    gamma * W_halt[(h * 3 + 2) * 3 + j] + b_halt[h * 3 + j];
        float mx = fmaxf(lg[0], fmaxf(lg[1], lg[2]));
        float e0 = expf(lg[0] - mx), e1 = expf(lg[1] - mx), e2 = expf(lg[2] - mx);
        float p_halt = (e0 + e1) / (e0 + e1 + e2);
        float cm = cum[idxb + h];
        int hl = halted[idxb + h];
        float would = cm + p_halt;
        int halts_now = (would >= THRESHV) || is_last;
        int active = hl ? 0 : 1;
        wgt[h]  = active ? (halts_now ? (1.0f - cm) : p_halt) : 0.0f;
        addc[h] = active ? p_halt : 0.0f;
        newcum[h] = (active && !halts_now) ? would : cm;
        newhl[h]  = hl || (active && halts_now);
    }
    __syncthreads();
    if (tid < HH) {
        cost[idxb + tid] += addc[tid];
        cum[idxb + tid] = newcum[tid];
        halted[idxb + tid] = newhl[tid];
    }
    float hwv[4];
    #pragma unroll
    for (int h = 0; h < HH; h++) hwv[h] = (he[h] / hsum) * wgt[h];

    size_t mo = (size_t)b * FF + t4;
    float4 m4 = *(const float4*)&merged[mo];
    m4.x += hwv[0] * a0.x + hwv[1] * a1.x + hwv[2] * a2.x + hwv[3] * a3.x;
    m4.y += hwv[0] * a0.y + hwv[1] * a1.y + hwv[2] * a2.y + hwv[3] * a3.y;
    m4.z += hwv[0] * a0.z + hwv[1] * a1.z + hwv[2] * a2.z + hwv[3] * a3.z;
    m4.w += hwv[0] * a0.w + hwv[1] * a1.w + hwv[2] * a2.w + hwv[3] * a3.w;
    *(float4*)&merged[mo] = m4;

    us4 fb;
    fb.x = f2bf(pool.x); fb.y = f2bf(pool.y); fb.z = f2bf(pool.z); fb.w = f2bf(pool.w);
    *(us4*)&feat[mo] = fb;
}

// ---------------- final output ----------------
__global__ void k_out(const float* __restrict__ psi, const float* __restrict__ merged,
                      const float* __restrict__ out_scale, float* __restrict__ out, int total) {
    int i = blockIdx.x * 256 + threadIdx.x;
    if (i >= total) return;
    float p = psi[i];
    out[i] = p + out_scale[0] * (merged[i] - p);
}

__global__ void k_costmean(const float* __restrict__ cost, float* __restrict__ out, int n) {
    __shared__ float red[256];
    int tid = threadIdx.x;
    float s = 0.f;
    for (int i = tid; i < n; i += 256) s += cost[i];
    red[tid] = s; __syncthreads();
    for (int off = 128; off > 0; off >>= 1) {
        if (tid < off) red[tid] += red[tid + off];
        __syncthreads();
    }
    if (tid == 0) out[0] = red[0] / (float)n;
}

extern "C" void kernel_launch(void* const* d_in, const int* in_sizes, int n_in,
                              void* d_out, int out_size, void* d_ws, size_t ws_size,
                              hipStream_t stream) {
    const float* psi       = (const float*)d_in[0];
    const float* bank_keys = (const float*)d_in[1];
    const float* bank_vals = (const float*)d_in[2];
    const float* u_halt    = (const float*)d_in[3];
    const float* W_halt    = (const float*)d_in[4];
    const float* b_halt    = (const float*)d_in[5];
    const float* head_mix  = (const float*)d_in[6];
    const float* out_scale = (const float*)d_in[7];
    float* out = (float*)d_out;

    const int BT = in_sizes[0] / FF;    // 4096

    float* ws = (float*)d_ws;
    size_t off = 0;
    float* psi_h  = ws + off; off += (size_t)BT * HH * FF;
    float* merged = ws + off; off += (size_t)BT * FF;     // zero region starts here
    float* cum    = ws + off; off += (size_t)BT * HH;
    float* costv  = ws + off; off += (size_t)BT * HH;
    int*   halted = (int*)(ws + off); off += (size_t)BT * HH;
    float* norminv = ws + off; off += 16;
    float* pbuf   = ws + off; off += (size_t)BT * NCB * 12;
    ushort_t* feat_bf = (ushort_t*)(ws + off); off += (size_t)BT * FF / 2;
    ushort_t* keys_bf = (ushort_t*)(ws + off); off += (size_t)HH * NN * FF / 2;

    hipMemsetAsync(merged, 0, ((size_t)BT * FF + 3 * (size_t)BT * HH) * sizeof(float), stream);
    k_unorm<<<1, 256, 0, stream>>>(u_halt, norminv);
    int tot_keys = HH * NN * FF;
    k_cvt_bf<<<(tot_keys + 255) / 256, 256, 0, stream>>>(bank_keys, keys_bf, tot_keys);
    int tot_bf = BT * FF;
    k_cvt_bf<<<(tot_bf + 255) / 256, 256, 0, stream>>>(psi, feat_bf, tot_bf);  // iter-0 feat = psi

    for (int it = 0; it < TMAXI; ++it) {
        k_gemm_topk<<<dim3(NCB, BT / 128), 256, 0, stream>>>(feat_bf, keys_bf, pbuf);
        k_fused<<<BT, 256, 0, stream>>>(psi, psi_h, bank_vals, pbuf, u_halt, norminv,
                                        W_halt, b_halt, head_mix, merged, feat_bf,
                                        cum, costv, halted,
                                        (it == 0) ? 1 : 0, (it == TMAXI - 1) ? 1 : 0);
    }
    k_out<<<(tot_bf + 255) / 256, 256, 0, stream>>>(psi, merged, out_scale, out, tot_bf);
    k_costmean<<<1, 256, 0, stream>>>(costv, out + tot_bf, BT * HH);
}